// Round 4
// baseline (369.913 us; speedup 1.0000x reference)
//
#include <hip/hip_runtime.h>
#include <hip/hip_bf16.h>
#include <cstdint>
#include <cstddef>

// Problem constants
#define BB   2
#define SS   2048
#define HIDD 2048
#define HH   16
#define KVH  4
#define DD   128
#define NQKV 5120   // H*2*D + KV*D + KV*D = 4096 + 512 + 512
#define MM   4096   // B*S

typedef unsigned short u16t;
typedef __attribute__((ext_vector_type(8))) short s16x8;
typedef __attribute__((ext_vector_type(4))) short s16x4;
typedef __attribute__((ext_vector_type(4))) float f32x4;

__device__ __forceinline__ u16t f2bf(float f) {
  unsigned u = __float_as_uint(f);
  u += 0x7fffu + ((u >> 16) & 1u);
  return (u16t)(u >> 16);
}
__device__ __forceinline__ float bf2f(u16t h) {
  return __uint_as_float(((unsigned)h) << 16);
}
__device__ __forceinline__ void gload_lds16(const void* g, void* l) {
  __builtin_amdgcn_global_load_lds(
      (const __attribute__((address_space(1))) unsigned int*)g,
      (__attribute__((address_space(3))) unsigned int*)l, 16, 0, 0);
}

// ---------------------------------------------------------------- cast f32->bf16
__global__ __launch_bounds__(256) void cast_x(const float* __restrict__ in,
                                              u16t* __restrict__ out) {
  size_t i = ((size_t)blockIdx.x * 256 + threadIdx.x) * 4;
  f32x4 v = *(const f32x4*)(in + i);
  s16x4 o;
  o[0] = (short)f2bf(v[0]); o[1] = (short)f2bf(v[1]);
  o[2] = (short)f2bf(v[2]); o[3] = (short)f2bf(v[3]);
  *(s16x4*)(out + i) = o;
}

// -------------------------------------------- transpose-cast W (K=2048,N) -> Wt (N,2048) bf16
__global__ __launch_bounds__(256) void transpose_cast(const float* __restrict__ src,
                                                      u16t* __restrict__ dst, int N) {
  __shared__ float lds[64 * 65];
  int t = threadIdx.x;
  const int ktiles = HIDD / 64; // 32
  int n0 = (blockIdx.x / ktiles) << 6;
  int k0 = (blockIdx.x % ktiles) << 6;
#pragma unroll
  for (int i = 0; i < 16; i++) {
    int idx = i * 256 + t;
    int r = idx >> 6, c = idx & 63;
    lds[c * 65 + r] = src[(size_t)(k0 + r) * N + n0 + c];
  }
  __syncthreads();
#pragma unroll
  for (int i = 0; i < 16; i++) {
    int idx = i * 256 + t;
    int rr = idx >> 6, kk = idx & 63;
    dst[(size_t)(n0 + rr) * HIDD + k0 + kk] = f2bf(lds[rr * 65 + kk]);
  }
}

// ---------------------------------------------------------------- 256x256 8-phase bf16 GEMM
// C(MxN,f32) = A(MxK,bf16 rm) @ Bt(NxK,bf16 rm)^T.  BK=64 (2 K-halves of 32).
__device__ __forceinline__ s16x8 ldsfrag(const char* half, int r, int g) {
  return *(const s16x8*)(half + r * 64 + ((g ^ ((r >> 1) & 3)) << 4));
}
__device__ __forceinline__ void stage_half(char* ldsbase, const u16t* gbase,
                                           int K, int kcol, int tid) {
#pragma unroll
  for (int i = 0; i < 2; i++) {
    int o16 = i * 512 + tid;
    int r = o16 >> 2;
    int cs = (o16 & 3) ^ ((r >> 1) & 3);
    gload_lds16(gbase + (size_t)r * K + kcol + cs * 8, ldsbase + o16 * 16);
  }
}

__global__ __launch_bounds__(512, 2) void gemm8(const u16t* __restrict__ A,
                                                const u16t* __restrict__ Bt,
                                                float* __restrict__ C,
                                                int M, int N, int K) {
  extern __shared__ __align__(16) char lds[];
  char* As = lds;           // [slot:32768][kk:16384]
  char* Bs = lds + 65536;
  int tid = threadIdx.x, lane = tid & 63, w = tid >> 6;
  int wm = w >> 2, wn = w & 3;
  int cpx = gridDim.x >> 3;                       // grid % 8 == 0
  int wgid = (blockIdx.x & 7) * cpx + (blockIdx.x >> 3);
  int bm = wgid & 15, bn = wgid >> 4;             // M/256 == 16
  int m0 = bm << 8, n0 = bn << 8;
  const u16t* Ag = A + (size_t)m0 * K;
  const u16t* Bg = Bt + (size_t)n0 * K;
  const int NT = K >> 6;

  // prologue: Ah0(0) Bh0(0) Ah1(0) Bh1(0) Ah0(1) Bh0(1)  (12 loads)
  stage_half(As, Ag, K, 0, tid);
  stage_half(Bs, Bg, K, 0, tid);
  stage_half(As + 16384, Ag, K, 32, tid);
  stage_half(Bs + 16384, Bg, K, 32, tid);
  stage_half(As + 32768, Ag, K, 64, tid);
  stage_half(Bs + 32768, Bg, K, 64, tid);
  asm volatile("s_waitcnt vmcnt(8)" ::: "memory");
  __builtin_amdgcn_s_barrier();

  const f32x4 fz = {0.f, 0.f, 0.f, 0.f};
  f32x4 acc[8][4];
#pragma unroll
  for (int i = 0; i < 8; i++)
#pragma unroll
    for (int j = 0; j < 4; j++) acc[i][j] = fz;
  s16x8 afr[4], bfr[4];
  int g = lane >> 4;
  int rA = (lane & 15) + wm * 128;
  int rB = (lane & 15) + wn * 64;

  for (int kt = 0; kt < NT; kt++) {
    int cur = kt & 1;
    char* Acur = As + cur * 32768;
    char* Bcur = Bs + cur * 32768;
    char* Anxt = As + (cur ^ 1) * 32768;
    char* Bnxt = Bs + (cur ^ 1) * 32768;
    // ---- phase 0: (kk0, mh0); stage Ah1(kt+1)
#pragma unroll
    for (int ni = 0; ni < 4; ni++) bfr[ni] = ldsfrag(Bcur, rB + ni * 16, g);
#pragma unroll
    for (int mi = 0; mi < 4; mi++) afr[mi] = ldsfrag(Acur, rA + mi * 16, g);
    if (kt + 1 < NT) stage_half(Anxt + 16384, Ag, K, (kt + 1) * 64 + 32, tid);
    __builtin_amdgcn_s_barrier();
    asm volatile("s_waitcnt lgkmcnt(0)" ::: "memory");
    __builtin_amdgcn_s_setprio(1);
#pragma unroll
    for (int mi = 0; mi < 4; mi++)
#pragma unroll
      for (int ni = 0; ni < 4; ni++)
        acc[mi][ni] = __builtin_amdgcn_mfma_f32_16x16x32_bf16(afr[mi], bfr[ni], acc[mi][ni], 0, 0, 0);
    __builtin_amdgcn_s_setprio(0);
    __builtin_amdgcn_s_barrier();
    // ---- phase 1: (kk0, mh1); stage Bh1(kt+1); counted wait
#pragma unroll
    for (int mi = 0; mi < 4; mi++) afr[mi] = ldsfrag(Acur, rA + 64 + mi * 16, g);
    if (kt + 1 < NT) stage_half(Bnxt + 16384, Bg, K, (kt + 1) * 64 + 32, tid);
    __builtin_amdgcn_s_barrier();
    asm volatile("s_waitcnt lgkmcnt(0)" ::: "memory");
    __builtin_amdgcn_s_setprio(1);
#pragma unroll
    for (int mi = 0; mi < 4; mi++)
#pragma unroll
      for (int ni = 0; ni < 4; ni++)
        acc[4 + mi][ni] = __builtin_amdgcn_mfma_f32_16x16x32_bf16(afr[mi], bfr[ni], acc[4 + mi][ni], 0, 0, 0);
    __builtin_amdgcn_s_setprio(0);
    if (kt + 1 < NT) asm volatile("s_waitcnt vmcnt(8)" ::: "memory");
    else             asm volatile("s_waitcnt vmcnt(0)" ::: "memory");
    __builtin_amdgcn_s_barrier();
    // ---- phase 2: (kk1, mh0); stage Ah0(kt+2)
#pragma unroll
    for (int ni = 0; ni < 4; ni++) bfr[ni] = ldsfrag(Bcur + 16384, rB + ni * 16, g);
#pragma unroll
    for (int mi = 0; mi < 4; mi++) afr[mi] = ldsfrag(Acur + 16384, rA + mi * 16, g);
    if (kt + 2 < NT) stage_half(Acur, Ag, K, (kt + 2) * 64, tid);
    __builtin_amdgcn_s_barrier();
    asm volatile("s_waitcnt lgkmcnt(0)" ::: "memory");
    __builtin_amdgcn_s_setprio(1);
#pragma unroll
    for (int mi = 0; mi < 4; mi++)
#pragma unroll
      for (int ni = 0; ni < 4; ni++)
        acc[mi][ni] = __builtin_amdgcn_mfma_f32_16x16x32_bf16(afr[mi], bfr[ni], acc[mi][ni], 0, 0, 0);
    __builtin_amdgcn_s_setprio(0);
    __builtin_amdgcn_s_barrier();
    // ---- phase 3: (kk1, mh1); stage Bh0(kt+2); counted wait
#pragma unroll
    for (int mi = 0; mi < 4; mi++) afr[mi] = ldsfrag(Acur + 16384, rA + 64 + mi * 16, g);
    if (kt + 2 < NT) stage_half(Bcur, Bg, K, (kt + 2) * 64, tid);
    __builtin_amdgcn_s_barrier();
    asm volatile("s_waitcnt lgkmcnt(0)" ::: "memory");
    __builtin_amdgcn_s_setprio(1);
#pragma unroll
    for (int mi = 0; mi < 4; mi++)
#pragma unroll
      for (int ni = 0; ni < 4; ni++)
        acc[4 + mi][ni] = __builtin_amdgcn_mfma_f32_16x16x32_bf16(afr[mi], bfr[ni], acc[4 + mi][ni], 0, 0, 0);
    __builtin_amdgcn_s_setprio(0);
    if (kt < NT - 1) {
      if (kt + 2 < NT) asm volatile("s_waitcnt vmcnt(8)" ::: "memory");
      else             asm volatile("s_waitcnt vmcnt(4)" ::: "memory");
    }
    __builtin_amdgcn_s_barrier();
  }
  // epilogue: C write (f32)
#pragma unroll
  for (int mi = 0; mi < 8; mi++)
#pragma unroll
    for (int ni = 0; ni < 4; ni++) {
      int row0 = m0 + wm * 128 + mi * 16 + ((lane >> 4) << 2);
      int col = n0 + wn * 64 + ni * 16 + (lane & 15);
#pragma unroll
      for (int j = 0; j < 4; j++)
        C[(size_t)(row0 + j) * N + col] = acc[mi][ni][j];
    }
}

// ------------------------------------------------- fused RMSNorm + RoPE for Q and K
// wave-per-row. Q rows: B*S*H (65536), then K rows: B*S*KV (16384)
__global__ __launch_bounds__(256) void qk_norm_rope(const float* __restrict__ Cqkv,
                                                    const float* __restrict__ rope,
                                                    const float* __restrict__ qw,
                                                    const float* __restrict__ kw,
                                                    u16t* __restrict__ Qb,   // (B,H,S,D)
                                                    u16t* __restrict__ Kb,   // (B,KV,S,D)
                                                    u16t* __restrict__ Gs,   // (B,S,H*D)
                                                    float* __restrict__ present) {
  int wid = blockIdx.x * 4 + (threadIdx.x >> 6);
  int lane = threadIdx.x & 63;
  const int NQ = BB * SS * HH; // 65536
  if (wid < NQ) {
    int b = wid >> 15;          // S*H = 32768
    int rem = wid & 32767;
    int s = rem >> 4, h = rem & 15;
    const float* base = Cqkv + (size_t)(b * SS + s) * NQKV + h * 256;
    float xlo = base[lane], xhi = base[64 + lane];
    float ss = xlo * xlo + xhi * xhi;
    ss += __shfl_xor(ss, 1);  ss += __shfl_xor(ss, 2);  ss += __shfl_xor(ss, 4);
    ss += __shfl_xor(ss, 8);  ss += __shfl_xor(ss, 16); ss += __shfl_xor(ss, 32);
    float r = rsqrtf(ss * (1.f / 128.f) + 1e-6f);
    float qlo = xlo * r * (1.f + qw[lane]);
    float qhi = xhi * r * (1.f + qw[64 + lane]);
    const float* cs = rope + (size_t)s * 256;
    float clo = cs[lane], chi = cs[64 + lane];
    float slo = cs[128 + lane], shi = cs[192 + lane];
    const float SC = 0.08838834764831845f; // 1/sqrt(128), folded into Q
    float olo = (qlo * clo - qhi * slo) * SC;
    float ohi = (qhi * chi + qlo * shi) * SC;
    size_t qoff = (((size_t)b * HH + h) * SS + s) * DD;
    Qb[qoff + lane] = f2bf(olo);
    Qb[qoff + 64 + lane] = f2bf(ohi);
    float glo = base[128 + lane], ghi = base[192 + lane];
    size_t goff = ((size_t)(b * SS + s)) * (HH * DD) + h * DD;
    Gs[goff + lane] = f2bf(1.f / (1.f + __expf(-glo)));
    Gs[goff + 64 + lane] = f2bf(1.f / (1.f + __expf(-ghi)));
  } else {
    int wid2 = wid - NQ;        // (b, s, kv): per b = S*KV = 8192
    int b = wid2 >> 13;
    int rem = wid2 & 8191;
    int s = rem >> 2, kv = rem & 3;
    const float* base = Cqkv + (size_t)(b * SS + s) * NQKV + 4096 + kv * 128;
    float xlo = base[lane], xhi = base[64 + lane];
    float ss = xlo * xlo + xhi * xhi;
    ss += __shfl_xor(ss, 1);  ss += __shfl_xor(ss, 2);  ss += __shfl_xor(ss, 4);
    ss += __shfl_xor(ss, 8);  ss += __shfl_xor(ss, 16); ss += __shfl_xor(ss, 32);
    float r = rsqrtf(ss * (1.f / 128.f) + 1e-6f);
    float klo = xlo * r * (1.f + kw[lane]);
    float khi = xhi * r * (1.f + kw[64 + lane]);
    const float* cs = rope + (size_t)s * 256;
    float clo = cs[lane], chi = cs[64 + lane];
    float slo = cs[128 + lane], shi = cs[192 + lane];
    float olo = klo * clo - khi * slo;
    float ohi = khi * chi + klo * shi;
    size_t koff = (((size_t)b * KVH + kv) * SS + s) * DD;
    Kb[koff + lane] = f2bf(olo);
    Kb[koff + 64 + lane] = f2bf(ohi);
    // present[b][0][kv][s][d]
    size_t poff = (((size_t)(b * 2 * KVH + kv)) * SS + s) * DD;
    present[poff + lane] = olo;
    present[poff + 64 + lane] = ohi;
  }
}

// ------------------------------------------------- V: present write + V^T bf16 (B,KV,D,S)
__global__ __launch_bounds__(256) void v_write(const float* __restrict__ Cqkv,
                                               float* __restrict__ present,
                                               u16t* __restrict__ Vtb) {
  __shared__ float lds[128 * 65];
  int t = threadIdx.x;
  int b = blockIdx.x >> 7;
  int kv = (blockIdx.x >> 5) & 3;
  int s0 = (blockIdx.x & 31) << 6;
#pragma unroll
  for (int i = 0; i < 32; i++) {
    int idx = i * 256 + t;
    int sp = idx >> 7, d = idx & 127;
    float v = Cqkv[(size_t)(b * SS + s0 + sp) * NQKV + 4608 + kv * 128 + d];
    // present[b][1][kv][s][d]
    present[(((size_t)(b * 2 * KVH + KVH + kv)) * SS + s0 + sp) * DD + d] = v;
    lds[d * 65 + sp] = v;
  }
  __syncthreads();
#pragma unroll
  for (int i = 0; i < 8; i++) {
    int d = i * 16 + (t >> 4);
    int sp = (t & 15) * 4;
    s16x4 pk;
    pk[0] = (short)f2bf(lds[d * 65 + sp + 0]);
    pk[1] = (short)f2bf(lds[d * 65 + sp + 1]);
    pk[2] = (short)f2bf(lds[d * 65 + sp + 2]);
    pk[3] = (short)f2bf(lds[d * 65 + sp + 3]);
    *(s16x4*)(Vtb + ((size_t)(b * KVH + kv) * DD + d) * SS + s0 + sp) = pk;
  }
}

// ---------------------------------------------------------------- flash attention
// block = 4 waves; QBLK=64 (wave w owns 16 q-rows); KVBLK=64; causal.
// LDS = Ks 16K + Vs 16K + Ps 8K = 40960 B -> 4 blocks/CU.
// Load-balanced mapping: XCD x = bid&7 owns (b,kv) = (x>>2, x&3) (KV L2-resident);
// within XCD, k = bid>>3: slot s=k>>5 (-> h), c=k&31, qt=(s&1)?c:31-c, so the 4
// blocks co-resident on a CU (k = c mod 32) sum to exactly 66 KV-tiles.
// Split-wait staging: issue K(4 loads) then V(4 loads); vmcnt(4)+bar -> QK+softmax
// (V in flight); vmcnt(0)+bar -> PV. Never a full drain before QK.
__global__ __launch_bounds__(256) void attn_kernel(const u16t* __restrict__ Qb,   // (B,H,S,D) pre-scaled
                                                   const u16t* __restrict__ Kb,   // (B,KV,S,D)
                                                   const u16t* __restrict__ Vtb,  // (B,KV,D,S)
                                                   const u16t* __restrict__ Gs,   // (B,S,H*D)
                                                   u16t* __restrict__ AttG) {     // (B,S,H*D)
  __shared__ __align__(16) char Ks[64 * 256];
  __shared__ __align__(16) char Vs[128 * 128];  // V^T: 128 rows x 128B, 8 chunks/row, xor (d&7)
  __shared__ __align__(16) char Ps[4 * 16 * 128]; // per-wave P: 16 rows x 128B, chunk xor (r&7)

  int tid = threadIdx.x, lane = tid & 63, w = tid >> 6;
  int x = blockIdx.x & 7;
  int k = blockIdx.x >> 3;           // 0..127
  int b = x >> 2, kv = x & 3;
  int s = k >> 5, c = k & 31;
  int h = kv * 4 + s;
  int qt = (s & 1) ? c : (31 - c);

  const u16t* Qbase = Qb + (((size_t)(b * HH + h)) * SS + qt * 64) * DD;
  const u16t* Kbase = Kb + (((size_t)(b * KVH + kv)) * SS) * DD;
  const u16t* Vbase = Vtb + (((size_t)(b * KVH + kv)) * DD) * SS;

  // Q fragments straight from global: row = w*16 + (lane&15), k = ks*32 + (lane>>4)*8
  s16x8 qf[4];
  {
    const u16t* qrow = Qbase + (size_t)(w * 16 + (lane & 15)) * DD + (lane >> 4) * 8;
#pragma unroll
    for (int ks = 0; ks < 4; ks++) qf[ks] = *(const s16x8*)(qrow + ks * 32);
  }

  const f32x4 fz = {0.f, 0.f, 0.f, 0.f};
  f32x4 acco[8];
#pragma unroll
  for (int f = 0; f < 8; f++) acco[f] = fz;
  float mrun[4], lrun[4];
#pragma unroll
  for (int j = 0; j < 4; j++) { mrun[j] = -INFINITY; lrun[j] = 0.f; }

  for (int kt = 0; kt <= qt; kt++) {
    __syncthreads();   // prev-iter LDS reads done before restage (vmcnt already 0 here)
    // K stage: 4 loads per thread
#pragma unroll
    for (int i = 0; i < 4; i++) {
      int idx = i * 256 + tid;
      int r = idx >> 4, cc = idx & 15;
      gload_lds16(Kbase + (size_t)(kt * 64 + r) * DD + (cc ^ (r & 7)) * 8, Ks + idx * 16);
    }
    // V stage: 4 loads per thread (completes under QK+softmax)
#pragma unroll
    for (int i = 0; i < 4; i++) {
      int idx = i * 256 + tid;
      int r = idx >> 3, cc = idx & 7;
      gload_lds16(Vbase + (size_t)r * SS + kt * 64 + (cc ^ (r & 7)) * 8, Vs + idx * 16);
    }
    asm volatile("s_waitcnt vmcnt(4)" ::: "memory");  // own K loads landed
    __builtin_amdgcn_s_barrier();                      // all waves' K landed

    f32x4 accs[4];
#pragma unroll
    for (int ni = 0; ni < 4; ni++) accs[ni] = fz;
#pragma unroll
    for (int ni = 0; ni < 4; ni++) {
      int r = ni * 16 + (lane & 15);
#pragma unroll
      for (int ks = 0; ks < 4; ks++) {
        int g = ks * 4 + (lane >> 4);
        s16x8 bfk = *(const s16x8*)(Ks + r * 256 + ((g ^ (r & 7)) << 4));
        accs[ni] = __builtin_amdgcn_mfma_f32_16x16x32_bf16(qf[ks], bfk, accs[ni], 0, 0, 0);
      }
    }
    if (kt == qt) {
#pragma unroll
      for (int ni = 0; ni < 4; ni++) {
        int col = ni * 16 + (lane & 15);
#pragma unroll
        for (int j = 0; j < 4; j++) {
          int row = w * 16 + ((lane >> 4) << 2) + j;
          if (col > row) accs[ni][j] = -1e30f;
        }
      }
    }
    float mt[4];
#pragma unroll
    for (int j = 0; j < 4; j++) {
      float v = fmaxf(fmaxf(accs[0][j], accs[1][j]), fmaxf(accs[2][j], accs[3][j]));
      v = fmaxf(v, __shfl_xor(v, 1));
      v = fmaxf(v, __shfl_xor(v, 2));
      v = fmaxf(v, __shfl_xor(v, 4));
      v = fmaxf(v, __shfl_xor(v, 8));
      mt[j] = v;
    }
    float alpha[4];
#pragma unroll
    for (int j = 0; j < 4; j++) {
      float mnew = fmaxf(mrun[j], mt[j]);
      alpha[j] = __expf(mrun[j] - mnew);
      mrun[j] = mnew;
    }
    float rs[4] = {0.f, 0.f, 0.f, 0.f};
#pragma unroll
    for (int ni = 0; ni < 4; ni++)
#pragma unroll
      for (int j = 0; j < 4; j++) {
        float p = __expf(accs[ni][j] - mrun[j]);
        accs[ni][j] = p;
        rs[j] += p;
      }
#pragma unroll
    for (int j = 0; j < 4; j++) {
      float v = rs[j];
      v += __shfl_xor(v, 1); v += __shfl_xor(v, 2);
      v += __shfl_xor(v, 4); v += __shfl_xor(v, 8);
      lrun[j] = lrun[j] * alpha[j] + v;
    }
#pragma unroll
    for (int f = 0; f < 8; f++)
#pragma unroll
      for (int j = 0; j < 4; j++) acco[f][j] *= alpha[j];

    char* pbase = Ps + w * 2048;
#pragma unroll
    for (int ni = 0; ni < 4; ni++)
#pragma unroll
      for (int j = 0; j < 4; j++) {
        int row = ((lane >> 4) << 2) + j, col = ni * 16 + (lane & 15);
        int ch = (col >> 3) ^ (row & 7);
        *(u16t*)(pbase + row * 128 + ch * 16 + (col & 7) * 2) = f2bf(accs[ni][j]);
      }
    asm volatile("s_waitcnt vmcnt(0)" ::: "memory");  // own V loads landed
    __builtin_amdgcn_s_barrier();                      // all waves' V landed
#pragma unroll
    for (int ks = 0; ks < 2; ks++) {
      int pr = lane & 15;
      int pch = (ks * 4 + (lane >> 4)) ^ (pr & 7);
      s16x8 pa = *(const s16x8*)(pbase + pr * 128 + (pch << 4));
#pragma unroll
      for (int f = 0; f < 8; f++) {
        int d = f * 16 + (lane & 15);
        int g = ks * 4 + (lane >> 4);
        s16x8 vf = *(const s16x8*)(Vs + d * 128 + ((g ^ (d & 7)) << 4));
        acco[f] = __builtin_amdgcn_mfma_f32_16x16x32_bf16(pa, vf, acco[f], 0, 0, 0);
      }
    }
  }
#pragma unroll
  for (int f = 0; f < 8; f++) {
    int d = f * 16 + (lane & 15);
#pragma unroll
    for (int j = 0; j < 4; j++) {
      int srow = qt * 64 + w * 16 + ((lane >> 4) << 2) + j;
      float o = acco[f][j] / lrun[j];
      size_t off = ((size_t)b * SS + srow) * (HH * DD) + h * DD + d;
      float g = bf2f(Gs[off]);
      AttG[off] = f2bf(o * g);
    }
  }
}

// ---------------------------------------------------------------- launcher
extern "C" void kernel_launch(void* const* d_in, const int* in_sizes, int n_in,
                              void* d_out, int out_size, void* d_ws, size_t ws_size,
                              hipStream_t stream) {
  const float* hidden = (const float*)d_in[0];
  const float* rope   = (const float*)d_in[2];
  const float* Wq     = (const float*)d_in[5];
  const float* Wk     = (const float*)d_in[6];
  const float* Wv     = (const float*)d_in[7];
  const float* Wo     = (const float*)d_in[8];
  const float* qw     = (const float*)d_in[9];
  const float* kw     = (const float*)d_in[10];
  float* out = (float*)d_out;
  float* present = out + (size_t)BB * SS * HIDD; // 8,388,608

  char* ws = (char*)d_ws;
  u16t* Xb   = (u16t*)(ws);                               // 4096x2048 bf16   16.78MB
  u16t* Wt   = (u16t*)(ws + 16777216);                    // 5120x2048 bf16   20.97MB
  u16t* Wot  = (u16t*)(ws + 37748736);                    // 2048x2048 bf16    8.39MB
  float* Cqkv = (float*)(ws + 46137344);                  // 4096x5120 f32    83.89MB
  u16t* Qb   = (u16t*)(ws + 130023424);                   // (B,H,S,D) bf16   16.78MB
  u16t* Kb   = (u16t*)(ws + 146800640);                   // (B,KV,S,D) bf16   4.19MB
  u16t* Vtb  = (u16t*)(ws + 150994944);                   // (B,KV,D,S) bf16   4.19MB
  u16t* Gs   = (u16t*)(ws + 155189248);                   // (B,S,H*D) bf16   16.78MB
  u16t* AttG = Xb;  // alias: Xb dead after QKV GEMM; AttG written by attention

  // allow 128KiB dynamic LDS for gemm8
  (void)hipFuncSetAttribute(reinterpret_cast<const void*>(gemm8),
                            hipFuncAttributeMaxDynamicSharedMemorySize, 131072);

  // 1. cast hidden -> bf16
  cast_x<<<8192, 256, 0, stream>>>(hidden, Xb);
  // 2. transpose-cast weights into B^T layout
  transpose_cast<<<(4096 / 64) * 32, 256, 0, stream>>>(Wq, Wt, 4096);
  transpose_cast<<<(512 / 64) * 32, 256, 0, stream>>>(Wk, Wt + (size_t)4096 * HIDD, 512);
  transpose_cast<<<(512 / 64) * 32, 256, 0, stream>>>(Wv, Wt + (size_t)4608 * HIDD, 512);
  transpose_cast<<<(2048 / 64) * 32, 256, 0, stream>>>(Wo, Wot, 2048);
  // 3. QKV projection: 256^2 8-phase GEMM, grid 16x20=320
  gemm8<<<(MM / 256) * (NQKV / 256), 512, 131072, stream>>>(Xb, Wt, Cqkv, MM, NQKV, HIDD);
  // 4. Q/K norm+rope (+present K, +sigmoid gate); V writer (+present V, +V^T)
  qk_norm_rope<<<(BB * SS * (HH + KVH)) / 4, 256, 0, stream>>>(Cqkv, rope, qw, kw, Qb, Kb, Gs, present);
  v_write<<<BB * KVH * (SS / 64), 256, 0, stream>>>(Cqkv, present, Vtb);
  // 5. flash attention (gated output, bf16, (B,S,H*D))
  attn_kernel<<<BB * HH * (SS / 64), 256, 0, stream>>>(Qb, Kb, Vtb, Gs, AttG);
  // 6. output projection -> d_out: grid 16x8=128
  gemm8<<<(MM / 256) * (HIDD / 256), 512, 131072, stream>>>(AttG, Wot, out, MM, HIDD, HIDD);
}

// Round 5
// 335.968 us; speedup vs baseline: 1.1010x; 1.1010x over previous
//
#include <hip/hip_runtime.h>
#include <hip/hip_bf16.h>
#include <cstdint>
#include <cstddef>

// Problem constants
#define BB   2
#define SS   2048
#define HIDD 2048
#define HH   16
#define KVH  4
#define DD   128
#define NQKV 5120   // H*2*D + KV*D + KV*D = 4096 + 512 + 512
#define MM   4096   // B*S

typedef unsigned short u16t;
typedef __attribute__((ext_vector_type(8))) short s16x8;
typedef __attribute__((ext_vector_type(4))) short s16x4;
typedef __attribute__((ext_vector_type(4))) float f32x4;

__device__ __forceinline__ u16t f2bf(float f) {
  unsigned u = __float_as_uint(f);
  u += 0x7fffu + ((u >> 16) & 1u);
  return (u16t)(u >> 16);
}
__device__ __forceinline__ float bf2f(u16t h) {
  return __uint_as_float(((unsigned)h) << 16);
}
__device__ __forceinline__ void gload_lds16(const void* g, void* l) {
  __builtin_amdgcn_global_load_lds(
      (const __attribute__((address_space(1))) unsigned int*)g,
      (__attribute__((address_space(3))) unsigned int*)l, 16, 0, 0);
}

// ---------------------------------------------------------------- cast f32->bf16
__global__ __launch_bounds__(256) void cast_x(const float* __restrict__ in,
                                              u16t* __restrict__ out) {
  size_t i = ((size_t)blockIdx.x * 256 + threadIdx.x) * 4;
  f32x4 v = *(const f32x4*)(in + i);
  s16x4 o;
  o[0] = (short)f2bf(v[0]); o[1] = (short)f2bf(v[1]);
  o[2] = (short)f2bf(v[2]); o[3] = (short)f2bf(v[3]);
  *(s16x4*)(out + i) = o;
}

// -------------------------------------------- transpose-cast W (K=2048,N) -> Wt (N,2048) bf16
__global__ __launch_bounds__(256) void transpose_cast(const float* __restrict__ src,
                                                      u16t* __restrict__ dst, int N) {
  __shared__ float lds[64 * 65];
  int t = threadIdx.x;
  const int ktiles = HIDD / 64; // 32
  int n0 = (blockIdx.x / ktiles) << 6;
  int k0 = (blockIdx.x % ktiles) << 6;
#pragma unroll
  for (int i = 0; i < 16; i++) {
    int idx = i * 256 + t;
    int r = idx >> 6, c = idx & 63;
    lds[c * 65 + r] = src[(size_t)(k0 + r) * N + n0 + c];
  }
  __syncthreads();
#pragma unroll
  for (int i = 0; i < 16; i++) {
    int idx = i * 256 + t;
    int rr = idx >> 6, kk = idx & 63;
    dst[(size_t)(n0 + rr) * HIDD + k0 + kk] = f2bf(lds[rr * 65 + kk]);
  }
}

// ---------------------------------------------------------------- 256x256 8-phase bf16 GEMM
// C(MxN,f32) = A(MxK,bf16 rm) @ Bt(NxK,bf16 rm)^T.  BK=64 (2 K-halves of 32).
__device__ __forceinline__ s16x8 ldsfrag(const char* half, int r, int g) {
  return *(const s16x8*)(half + r * 64 + ((g ^ ((r >> 1) & 3)) << 4));
}
__device__ __forceinline__ void stage_half(char* ldsbase, const u16t* gbase,
                                           int K, int kcol, int tid) {
#pragma unroll
  for (int i = 0; i < 2; i++) {
    int o16 = i * 512 + tid;
    int r = o16 >> 2;
    int cs = (o16 & 3) ^ ((r >> 1) & 3);
    gload_lds16(gbase + (size_t)r * K + kcol + cs * 8, ldsbase + o16 * 16);
  }
}

__global__ __launch_bounds__(512, 2) void gemm8(const u16t* __restrict__ A,
                                                const u16t* __restrict__ Bt,
                                                float* __restrict__ C,
                                                int M, int N, int K) {
  extern __shared__ __align__(16) char lds[];
  char* As = lds;           // [slot:32768][kk:16384]
  char* Bs = lds + 65536;
  int tid = threadIdx.x, lane = tid & 63, w = tid >> 6;
  int wm = w >> 2, wn = w & 3;
  int cpx = gridDim.x >> 3;                       // grid % 8 == 0
  int wgid = (blockIdx.x & 7) * cpx + (blockIdx.x >> 3);
  int bm = wgid & 15, bn = wgid >> 4;             // M/256 == 16
  int m0 = bm << 8, n0 = bn << 8;
  const u16t* Ag = A + (size_t)m0 * K;
  const u16t* Bg = Bt + (size_t)n0 * K;
  const int NT = K >> 6;

  // prologue: Ah0(0) Bh0(0) Ah1(0) Bh1(0) Ah0(1) Bh0(1)  (12 loads)
  stage_half(As, Ag, K, 0, tid);
  stage_half(Bs, Bg, K, 0, tid);
  stage_half(As + 16384, Ag, K, 32, tid);
  stage_half(Bs + 16384, Bg, K, 32, tid);
  stage_half(As + 32768, Ag, K, 64, tid);
  stage_half(Bs + 32768, Bg, K, 64, tid);
  asm volatile("s_waitcnt vmcnt(8)" ::: "memory");
  __builtin_amdgcn_s_barrier();

  const f32x4 fz = {0.f, 0.f, 0.f, 0.f};
  f32x4 acc[8][4];
#pragma unroll
  for (int i = 0; i < 8; i++)
#pragma unroll
    for (int j = 0; j < 4; j++) acc[i][j] = fz;
  s16x8 afr[4], bfr[4];
  int g = lane >> 4;
  int rA = (lane & 15) + wm * 128;
  int rB = (lane & 15) + wn * 64;

  for (int kt = 0; kt < NT; kt++) {
    int cur = kt & 1;
    char* Acur = As + cur * 32768;
    char* Bcur = Bs + cur * 32768;
    char* Anxt = As + (cur ^ 1) * 32768;
    char* Bnxt = Bs + (cur ^ 1) * 32768;
    // ---- phase 0: (kk0, mh0); stage Ah1(kt+1)
#pragma unroll
    for (int ni = 0; ni < 4; ni++) bfr[ni] = ldsfrag(Bcur, rB + ni * 16, g);
#pragma unroll
    for (int mi = 0; mi < 4; mi++) afr[mi] = ldsfrag(Acur, rA + mi * 16, g);
    if (kt + 1 < NT) stage_half(Anxt + 16384, Ag, K, (kt + 1) * 64 + 32, tid);
    __builtin_amdgcn_s_barrier();
    asm volatile("s_waitcnt lgkmcnt(0)" ::: "memory");
    __builtin_amdgcn_s_setprio(1);
#pragma unroll
    for (int mi = 0; mi < 4; mi++)
#pragma unroll
      for (int ni = 0; ni < 4; ni++)
        acc[mi][ni] = __builtin_amdgcn_mfma_f32_16x16x32_bf16(afr[mi], bfr[ni], acc[mi][ni], 0, 0, 0);
    __builtin_amdgcn_s_setprio(0);
    __builtin_amdgcn_s_barrier();
    // ---- phase 1: (kk0, mh1); stage Bh1(kt+1); counted wait
#pragma unroll
    for (int mi = 0; mi < 4; mi++) afr[mi] = ldsfrag(Acur, rA + 64 + mi * 16, g);
    if (kt + 1 < NT) stage_half(Bnxt + 16384, Bg, K, (kt + 1) * 64 + 32, tid);
    __builtin_amdgcn_s_barrier();
    asm volatile("s_waitcnt lgkmcnt(0)" ::: "memory");
    __builtin_amdgcn_s_setprio(1);
#pragma unroll
    for (int mi = 0; mi < 4; mi++)
#pragma unroll
      for (int ni = 0; ni < 4; ni++)
        acc[4 + mi][ni] = __builtin_amdgcn_mfma_f32_16x16x32_bf16(afr[mi], bfr[ni], acc[4 + mi][ni], 0, 0, 0);
    __builtin_amdgcn_s_setprio(0);
    if (kt + 1 < NT) asm volatile("s_waitcnt vmcnt(8)" ::: "memory");
    else             asm volatile("s_waitcnt vmcnt(0)" ::: "memory");
    __builtin_amdgcn_s_barrier();
    // ---- phase 2: (kk1, mh0); stage Ah0(kt+2)
#pragma unroll
    for (int ni = 0; ni < 4; ni++) bfr[ni] = ldsfrag(Bcur + 16384, rB + ni * 16, g);
#pragma unroll
    for (int mi = 0; mi < 4; mi++) afr[mi] = ldsfrag(Acur + 16384, rA + mi * 16, g);
    if (kt + 2 < NT) stage_half(Acur, Ag, K, (kt + 2) * 64, tid);
    __builtin_amdgcn_s_barrier();
    asm volatile("s_waitcnt lgkmcnt(0)" ::: "memory");
    __builtin_amdgcn_s_setprio(1);
#pragma unroll
    for (int mi = 0; mi < 4; mi++)
#pragma unroll
      for (int ni = 0; ni < 4; ni++)
        acc[mi][ni] = __builtin_amdgcn_mfma_f32_16x16x32_bf16(afr[mi], bfr[ni], acc[mi][ni], 0, 0, 0);
    __builtin_amdgcn_s_setprio(0);
    __builtin_amdgcn_s_barrier();
    // ---- phase 3: (kk1, mh1); stage Bh0(kt+2); counted wait
#pragma unroll
    for (int mi = 0; mi < 4; mi++) afr[mi] = ldsfrag(Acur + 16384, rA + 64 + mi * 16, g);
    if (kt + 2 < NT) stage_half(Bcur, Bg, K, (kt + 2) * 64, tid);
    __builtin_amdgcn_s_barrier();
    asm volatile("s_waitcnt lgkmcnt(0)" ::: "memory");
    __builtin_amdgcn_s_setprio(1);
#pragma unroll
    for (int mi = 0; mi < 4; mi++)
#pragma unroll
      for (int ni = 0; ni < 4; ni++)
        acc[4 + mi][ni] = __builtin_amdgcn_mfma_f32_16x16x32_bf16(afr[mi], bfr[ni], acc[4 + mi][ni], 0, 0, 0);
    __builtin_amdgcn_s_setprio(0);
    if (kt < NT - 1) {
      if (kt + 2 < NT) asm volatile("s_waitcnt vmcnt(8)" ::: "memory");
      else             asm volatile("s_waitcnt vmcnt(4)" ::: "memory");
    }
    __builtin_amdgcn_s_barrier();
  }
  // epilogue: C write (f32)
#pragma unroll
  for (int mi = 0; mi < 8; mi++)
#pragma unroll
    for (int ni = 0; ni < 4; ni++) {
      int row0 = m0 + wm * 128 + mi * 16 + ((lane >> 4) << 2);
      int col = n0 + wn * 64 + ni * 16 + (lane & 15);
#pragma unroll
      for (int j = 0; j < 4; j++)
        C[(size_t)(row0 + j) * N + col] = acc[mi][ni][j];
    }
}

// ------------------------------------------------- fused RMSNorm + RoPE for Q and K
// wave-per-row. Q rows: B*S*H (65536), then K rows: B*S*KV (16384)
__global__ __launch_bounds__(256) void qk_norm_rope(const float* __restrict__ Cqkv,
                                                    const float* __restrict__ rope,
                                                    const float* __restrict__ qw,
                                                    const float* __restrict__ kw,
                                                    u16t* __restrict__ Qb,   // (B,H,S,D)
                                                    u16t* __restrict__ Kb,   // (B,KV,S,D)
                                                    u16t* __restrict__ Gs,   // (B,S,H*D)
                                                    float* __restrict__ present) {
  int wid = blockIdx.x * 4 + (threadIdx.x >> 6);
  int lane = threadIdx.x & 63;
  const int NQ = BB * SS * HH; // 65536
  if (wid < NQ) {
    int b = wid >> 15;          // S*H = 32768
    int rem = wid & 32767;
    int s = rem >> 4, h = rem & 15;
    const float* base = Cqkv + (size_t)(b * SS + s) * NQKV + h * 256;
    float xlo = base[lane], xhi = base[64 + lane];
    float ss = xlo * xlo + xhi * xhi;
    ss += __shfl_xor(ss, 1);  ss += __shfl_xor(ss, 2);  ss += __shfl_xor(ss, 4);
    ss += __shfl_xor(ss, 8);  ss += __shfl_xor(ss, 16); ss += __shfl_xor(ss, 32);
    float r = rsqrtf(ss * (1.f / 128.f) + 1e-6f);
    float qlo = xlo * r * (1.f + qw[lane]);
    float qhi = xhi * r * (1.f + qw[64 + lane]);
    const float* cs = rope + (size_t)s * 256;
    float clo = cs[lane], chi = cs[64 + lane];
    float slo = cs[128 + lane], shi = cs[192 + lane];
    const float SC = 0.08838834764831845f; // 1/sqrt(128), folded into Q
    float olo = (qlo * clo - qhi * slo) * SC;
    float ohi = (qhi * chi + qlo * shi) * SC;
    size_t qoff = (((size_t)b * HH + h) * SS + s) * DD;
    Qb[qoff + lane] = f2bf(olo);
    Qb[qoff + 64 + lane] = f2bf(ohi);
    float glo = base[128 + lane], ghi = base[192 + lane];
    size_t goff = ((size_t)(b * SS + s)) * (HH * DD) + h * DD;
    Gs[goff + lane] = f2bf(1.f / (1.f + __expf(-glo)));
    Gs[goff + 64 + lane] = f2bf(1.f / (1.f + __expf(-ghi)));
  } else {
    int wid2 = wid - NQ;        // (b, s, kv): per b = S*KV = 8192
    int b = wid2 >> 13;
    int rem = wid2 & 8191;
    int s = rem >> 2, kv = rem & 3;
    const float* base = Cqkv + (size_t)(b * SS + s) * NQKV + 4096 + kv * 128;
    float xlo = base[lane], xhi = base[64 + lane];
    float ss = xlo * xlo + xhi * xhi;
    ss += __shfl_xor(ss, 1);  ss += __shfl_xor(ss, 2);  ss += __shfl_xor(ss, 4);
    ss += __shfl_xor(ss, 8);  ss += __shfl_xor(ss, 16); ss += __shfl_xor(ss, 32);
    float r = rsqrtf(ss * (1.f / 128.f) + 1e-6f);
    float klo = xlo * r * (1.f + kw[lane]);
    float khi = xhi * r * (1.f + kw[64 + lane]);
    const float* cs = rope + (size_t)s * 256;
    float clo = cs[lane], chi = cs[64 + lane];
    float slo = cs[128 + lane], shi = cs[192 + lane];
    float olo = klo * clo - khi * slo;
    float ohi = khi * chi + klo * shi;
    size_t koff = (((size_t)b * KVH + kv) * SS + s) * DD;
    Kb[koff + lane] = f2bf(olo);
    Kb[koff + 64 + lane] = f2bf(ohi);
    // present[b][0][kv][s][d]
    size_t poff = (((size_t)(b * 2 * KVH + kv)) * SS + s) * DD;
    present[poff + lane] = olo;
    present[poff + 64 + lane] = ohi;
  }
}

// ------------------------------------------------- V: present write + V^T bf16 (B,KV,D,S)
__global__ __launch_bounds__(256) void v_write(const float* __restrict__ Cqkv,
                                               float* __restrict__ present,
                                               u16t* __restrict__ Vtb) {
  __shared__ float lds[128 * 65];
  int t = threadIdx.x;
  int b = blockIdx.x >> 7;
  int kv = (blockIdx.x >> 5) & 3;
  int s0 = (blockIdx.x & 31) << 6;
#pragma unroll
  for (int i = 0; i < 32; i++) {
    int idx = i * 256 + t;
    int sp = idx >> 7, d = idx & 127;
    float v = Cqkv[(size_t)(b * SS + s0 + sp) * NQKV + 4608 + kv * 128 + d];
    // present[b][1][kv][s][d]
    present[(((size_t)(b * 2 * KVH + KVH + kv)) * SS + s0 + sp) * DD + d] = v;
    lds[d * 65 + sp] = v;
  }
  __syncthreads();
#pragma unroll
  for (int i = 0; i < 8; i++) {
    int d = i * 16 + (t >> 4);
    int sp = (t & 15) * 4;
    s16x4 pk;
    pk[0] = (short)f2bf(lds[d * 65 + sp + 0]);
    pk[1] = (short)f2bf(lds[d * 65 + sp + 1]);
    pk[2] = (short)f2bf(lds[d * 65 + sp + 2]);
    pk[3] = (short)f2bf(lds[d * 65 + sp + 3]);
    *(s16x4*)(Vtb + ((size_t)(b * KVH + kv) * DD + d) * SS + s0 + sp) = pk;
  }
}

// ---------------------------------------------------------------- flash attention
// block = 4 waves; KVBLK=64; causal. PAIRED q-tiles: block handles qt = 31-p then
// qt = p sequentially -> exactly 33 KV-tile-units per block, every block equal.
// Grid = B*KV*4h*16p = 512 = 2 blocks/CU; uniform duration, occupancy constant.
// K/V double-buffered (LDS 72KB -> 2 blocks/CU): next tile's stage issued at top
// of iteration, single vmcnt(0)+barrier at bottom -> stage hidden under compute.
__global__ __launch_bounds__(256) void attn_kernel(const u16t* __restrict__ Qb,   // (B,H,S,D) pre-scaled
                                                   const u16t* __restrict__ Kb,   // (B,KV,S,D)
                                                   const u16t* __restrict__ Vtb,  // (B,KV,D,S)
                                                   const u16t* __restrict__ Gs,   // (B,S,H*D)
                                                   u16t* __restrict__ AttG) {     // (B,S,H*D)
  __shared__ __align__(16) char Ks[2][16384];   // 64 rows x 256B, chunk xor (r&7)
  __shared__ __align__(16) char Vs[2][16384];   // V^T: 128 rows x 128B, chunk xor (d&7)
  __shared__ __align__(16) char Ps[4 * 2048];   // per-wave P: 16 rows x 128B, chunk xor

  int tid = threadIdx.x, lane = tid & 63, w = tid >> 6;
  int x = blockIdx.x & 7;          // XCD grouping: each XCD owns one (b,kv)
  int b = x >> 2, kv = x & 3;
  int rr = blockIdx.x >> 3;        // 0..63
  int h = kv * 4 + (rr & 3);
  int p = rr >> 2;                 // 0..15: pair {31-p, p}

  const u16t* Kbase = Kb + (((size_t)(b * KVH + kv)) * SS) * DD;
  const u16t* Vbase = Vtb + (((size_t)(b * KVH + kv)) * DD) * SS;

  auto stageK = [&](int kt, int buf) {
#pragma unroll
    for (int i = 0; i < 4; i++) {
      int idx = i * 256 + tid;
      int r_ = idx >> 4, c_ = idx & 15;
      gload_lds16(Kbase + (size_t)(kt * 64 + r_) * DD + (c_ ^ (r_ & 7)) * 8, Ks[buf] + idx * 16);
    }
  };
  auto stageV = [&](int kt, int buf) {
#pragma unroll
    for (int i = 0; i < 4; i++) {
      int idx = i * 256 + tid;
      int r_ = idx >> 3, c_ = idx & 7;
      gload_lds16(Vbase + (size_t)r_ * SS + kt * 64 + (c_ ^ (r_ & 7)) * 8, Vs[buf] + idx * 16);
    }
  };

  const f32x4 fz = {0.f, 0.f, 0.f, 0.f};
  char* pbase = Ps + w * 2048;
  int cur = 0;

  // prologue: stage tile 0 of segment 0 into buffer 0
  stageK(0, 0);
  stageV(0, 0);

  for (int seg = 0; seg < 2; seg++) {
    int qt = (seg == 0) ? (31 - p) : p;
    const u16t* Qbase = Qb + (((size_t)(b * HH + h)) * SS + qt * 64) * DD;
    s16x8 qf[4];
    {
      const u16t* qrow = Qbase + (size_t)(w * 16 + (lane & 15)) * DD + (lane >> 4) * 8;
#pragma unroll
      for (int ks = 0; ks < 4; ks++) qf[ks] = *(const s16x8*)(qrow + ks * 32);
    }
    f32x4 acco[8];
#pragma unroll
    for (int f = 0; f < 8; f++) acco[f] = fz;
    float mrun[4], lrun[4];
#pragma unroll
    for (int j = 0; j < 4; j++) { mrun[j] = -INFINITY; lrun[j] = 0.f; }

    if (seg == 0) {
      asm volatile("s_waitcnt vmcnt(0)" ::: "memory");
      __builtin_amdgcn_s_barrier();
    }

    for (int kt = 0; kt <= qt; kt++) {
      bool havenext = (kt < qt) || (seg == 0);
      if (havenext) {
        int nk = (kt < qt) ? (kt + 1) : 0;   // next tile, or seg1's tile 0
        stageK(nk, cur ^ 1);
        stageV(nk, cur ^ 1);
      }
      // ---- QK^T from Ks[cur]
      f32x4 accs[4];
#pragma unroll
      for (int ni = 0; ni < 4; ni++) accs[ni] = fz;
#pragma unroll
      for (int ni = 0; ni < 4; ni++) {
        int r = ni * 16 + (lane & 15);
#pragma unroll
        for (int ks = 0; ks < 4; ks++) {
          int g = ks * 4 + (lane >> 4);
          s16x8 bfk = *(const s16x8*)(Ks[cur] + r * 256 + ((g ^ (r & 7)) << 4));
          accs[ni] = __builtin_amdgcn_mfma_f32_16x16x32_bf16(qf[ks], bfk, accs[ni], 0, 0, 0);
        }
      }
      if (kt == qt) {
#pragma unroll
        for (int ni = 0; ni < 4; ni++) {
          int col = ni * 16 + (lane & 15);
#pragma unroll
          for (int j = 0; j < 4; j++) {
            int row = w * 16 + ((lane >> 4) << 2) + j;
            if (col > row) accs[ni][j] = -1e30f;
          }
        }
      }
      // ---- online softmax
      float mt[4];
#pragma unroll
      for (int j = 0; j < 4; j++) {
        float v = fmaxf(fmaxf(accs[0][j], accs[1][j]), fmaxf(accs[2][j], accs[3][j]));
        v = fmaxf(v, __shfl_xor(v, 1));
        v = fmaxf(v, __shfl_xor(v, 2));
        v = fmaxf(v, __shfl_xor(v, 4));
        v = fmaxf(v, __shfl_xor(v, 8));
        mt[j] = v;
      }
      float alpha[4];
#pragma unroll
      for (int j = 0; j < 4; j++) {
        float mnew = fmaxf(mrun[j], mt[j]);
        alpha[j] = __expf(mrun[j] - mnew);
        mrun[j] = mnew;
      }
      float rs[4] = {0.f, 0.f, 0.f, 0.f};
#pragma unroll
      for (int ni = 0; ni < 4; ni++)
#pragma unroll
        for (int j = 0; j < 4; j++) {
          float pv = __expf(accs[ni][j] - mrun[j]);
          accs[ni][j] = pv;
          rs[j] += pv;
        }
#pragma unroll
      for (int j = 0; j < 4; j++) {
        float v = rs[j];
        v += __shfl_xor(v, 1); v += __shfl_xor(v, 2);
        v += __shfl_xor(v, 4); v += __shfl_xor(v, 8);
        lrun[j] = lrun[j] * alpha[j] + v;
      }
#pragma unroll
      for (int f = 0; f < 8; f++)
#pragma unroll
        for (int j = 0; j < 4; j++) acco[f][j] *= alpha[j];

      // ---- P -> LDS (per-wave region)
#pragma unroll
      for (int ni = 0; ni < 4; ni++)
#pragma unroll
        for (int j = 0; j < 4; j++) {
          int row = ((lane >> 4) << 2) + j, col = ni * 16 + (lane & 15);
          int ch = (col >> 3) ^ (row & 7);
          *(u16t*)(pbase + row * 128 + ch * 16 + (col & 7) * 2) = f2bf(accs[ni][j]);
        }
      // ---- PV from Vs[cur]
#pragma unroll
      for (int ks = 0; ks < 2; ks++) {
        int pr = lane & 15;
        int pch = (ks * 4 + (lane >> 4)) ^ (pr & 7);
        s16x8 pa = *(const s16x8*)(pbase + pr * 128 + (pch << 4));
#pragma unroll
        for (int f = 0; f < 8; f++) {
          int d = f * 16 + (lane & 15);
          int g = ks * 4 + (lane >> 4);
          s16x8 vf = *(const s16x8*)(Vs[cur] + d * 128 + ((g ^ (d & 7)) << 4));
          acco[f] = __builtin_amdgcn_mfma_f32_16x16x32_bf16(pa, vf, acco[f], 0, 0, 0);
        }
      }
      // ---- tile boundary: next tile staged, current reads done
      if (havenext) {
        asm volatile("s_waitcnt vmcnt(0)" ::: "memory");
        __builtin_amdgcn_s_barrier();
        cur ^= 1;
      }
    }
    // ---- segment epilogue
#pragma unroll
    for (int f = 0; f < 8; f++) {
      int d = f * 16 + (lane & 15);
#pragma unroll
      for (int j = 0; j < 4; j++) {
        int srow = qt * 64 + w * 16 + ((lane >> 4) << 2) + j;
        float o = acco[f][j] / lrun[j];
        size_t off = ((size_t)b * SS + srow) * (HH * DD) + h * DD + d;
        float g = bf2f(Gs[off]);
        AttG[off] = f2bf(o * g);
      }
    }
  }
}

// ---------------------------------------------------------------- launcher
extern "C" void kernel_launch(void* const* d_in, const int* in_sizes, int n_in,
                              void* d_out, int out_size, void* d_ws, size_t ws_size,
                              hipStream_t stream) {
  const float* hidden = (const float*)d_in[0];
  const float* rope   = (const float*)d_in[2];
  const float* Wq     = (const float*)d_in[5];
  const float* Wk     = (const float*)d_in[6];
  const float* Wv     = (const float*)d_in[7];
  const float* Wo     = (const float*)d_in[8];
  const float* qw     = (const float*)d_in[9];
  const float* kw     = (const float*)d_in[10];
  float* out = (float*)d_out;
  float* present = out + (size_t)BB * SS * HIDD; // 8,388,608

  char* ws = (char*)d_ws;
  u16t* Xb   = (u16t*)(ws);                               // 4096x2048 bf16   16.78MB
  u16t* Wt   = (u16t*)(ws + 16777216);                    // 5120x2048 bf16   20.97MB
  u16t* Wot  = (u16t*)(ws + 37748736);                    // 2048x2048 bf16    8.39MB
  float* Cqkv = (float*)(ws + 46137344);                  // 4096x5120 f32    83.89MB
  u16t* Qb   = (u16t*)(ws + 130023424);                   // (B,H,S,D) bf16   16.78MB
  u16t* Kb   = (u16t*)(ws + 146800640);                   // (B,KV,S,D) bf16   4.19MB
  u16t* Vtb  = (u16t*)(ws + 150994944);                   // (B,KV,D,S) bf16   4.19MB
  u16t* Gs   = (u16t*)(ws + 155189248);                   // (B,S,H*D) bf16   16.78MB
  u16t* AttG = Xb;  // alias: Xb dead after QKV GEMM; AttG written by attention

  // allow 128KiB dynamic LDS for gemm8
  (void)hipFuncSetAttribute(reinterpret_cast<const void*>(gemm8),
                            hipFuncAttributeMaxDynamicSharedMemorySize, 131072);

  // 1. cast hidden -> bf16
  cast_x<<<8192, 256, 0, stream>>>(hidden, Xb);
  // 2. transpose-cast weights into B^T layout
  transpose_cast<<<(4096 / 64) * 32, 256, 0, stream>>>(Wq, Wt, 4096);
  transpose_cast<<<(512 / 64) * 32, 256, 0, stream>>>(Wk, Wt + (size_t)4096 * HIDD, 512);
  transpose_cast<<<(512 / 64) * 32, 256, 0, stream>>>(Wv, Wt + (size_t)4608 * HIDD, 512);
  transpose_cast<<<(2048 / 64) * 32, 256, 0, stream>>>(Wo, Wot, 2048);
  // 3. QKV projection: 256^2 8-phase GEMM, grid 16x20=320
  gemm8<<<(MM / 256) * (NQKV / 256), 512, 131072, stream>>>(Xb, Wt, Cqkv, MM, NQKV, HIDD);
  // 4. Q/K norm+rope (+present K, +sigmoid gate); V writer (+present V, +V^T)
  qk_norm_rope<<<(BB * SS * (HH + KVH)) / 4, 256, 0, stream>>>(Cqkv, rope, qw, kw, Qb, Kb, Gs, present);
  v_write<<<BB * KVH * (SS / 64), 256, 0, stream>>>(Cqkv, present, Vtb);
  // 5. flash attention: paired q-tiles, 512 uniform blocks
  attn_kernel<<<BB * HH * (SS / 128), 256, 0, stream>>>(Qb, Kb, Vtb, Gs, AttG);
  // 6. output projection -> d_out: grid 16x8=128
  gemm8<<<(MM / 256) * (HIDD / 256), 512, 131072, stream>>>(AttG, Wot, out, MM, HIDD, HIDD);
}

// Round 6
// 319.474 us; speedup vs baseline: 1.1579x; 1.0516x over previous
//
#include <hip/hip_runtime.h>
#include <hip/hip_bf16.h>
#include <cstdint>
#include <cstddef>

// Problem constants
#define BB   2
#define SS   2048
#define HIDD 2048
#define HH   16
#define KVH  4
#define DD   128
#define NQKV 5120   // H*2*D + KV*D + KV*D = 4096 + 512 + 512
#define MM   4096   // B*S

typedef unsigned short u16t;
typedef __attribute__((ext_vector_type(8))) short s16x8;
typedef __attribute__((ext_vector_type(4))) short s16x4;
typedef __attribute__((ext_vector_type(4))) float f32x4;

__device__ __forceinline__ u16t f2bf(float f) {
  unsigned u = __float_as_uint(f);
  u += 0x7fffu + ((u >> 16) & 1u);
  return (u16t)(u >> 16);
}
__device__ __forceinline__ float bf2f(u16t h) {
  return __uint_as_float(((unsigned)h) << 16);
}
__device__ __forceinline__ void gload_lds16(const void* g, void* l) {
  __builtin_amdgcn_global_load_lds(
      (const __attribute__((address_space(1))) unsigned int*)g,
      (__attribute__((address_space(3))) unsigned int*)l, 16, 0, 0);
}

// ---------------------------------------------------------------- cast f32->bf16
__global__ __launch_bounds__(256) void cast_x(const float* __restrict__ in,
                                              u16t* __restrict__ out) {
  size_t i = ((size_t)blockIdx.x * 256 + threadIdx.x) * 4;
  f32x4 v = *(const f32x4*)(in + i);
  s16x4 o;
  o[0] = (short)f2bf(v[0]); o[1] = (short)f2bf(v[1]);
  o[2] = (short)f2bf(v[2]); o[3] = (short)f2bf(v[3]);
  *(s16x4*)(out + i) = o;
}

// -------------------------------------------- transpose-cast W (K=2048,N) -> Wt (N,2048) bf16
__global__ __launch_bounds__(256) void transpose_cast(const float* __restrict__ src,
                                                      u16t* __restrict__ dst, int N) {
  __shared__ float lds[64 * 65];
  int t = threadIdx.x;
  const int ktiles = HIDD / 64; // 32
  int n0 = (blockIdx.x / ktiles) << 6;
  int k0 = (blockIdx.x % ktiles) << 6;
#pragma unroll
  for (int i = 0; i < 16; i++) {
    int idx = i * 256 + t;
    int r = idx >> 6, c = idx & 63;
    lds[c * 65 + r] = src[(size_t)(k0 + r) * N + n0 + c];
  }
  __syncthreads();
#pragma unroll
  for (int i = 0; i < 16; i++) {
    int idx = i * 256 + t;
    int rr = idx >> 6, kk = idx & 63;
    dst[(size_t)(n0 + rr) * HIDD + k0 + kk] = f2bf(lds[rr * 65 + kk]);
  }
}

// ---------------------------------------------------------------- 128x128 bf16 GEMM (m97 structure)
// C(MxN, CT) = A(MxK,bf16 rm) @ Bt(NxK,bf16 rm)^T.  BK=32.
// 4 waves (2x2), per-wave 64x64 out, acc[4][4] -> 64 AGPR + ~64 VGPR = 128/thread
// -> 4 waves/SIMD -> 4 blocks/CU. LDS 16KB. QKV grid 1280 = exactly 5 blocks/CU.
// 2-way LDS chunk swizzle c^((r>>1)&3) (free); XCD-chunked block swizzle.
template <typename CT>
__global__ __launch_bounds__(256) void gemm_bt(const u16t* __restrict__ A,
                                               const u16t* __restrict__ Bt,
                                               CT* __restrict__ C,
                                               int M, int N, int K) {
  __shared__ __align__(16) char As[128 * 64];
  __shared__ __align__(16) char Bs[128 * 64];
  int tid = threadIdx.x;
  int lane = tid & 63;
  int w = tid >> 6;
  // XCD-chunked bijective swizzle (grid % 8 == 0)
  int cpx = gridDim.x >> 3;
  int wgid = ((int)blockIdx.x & 7) * cpx + ((int)blockIdx.x >> 3);
  int mtiles = M >> 7;
  int bm = wgid % mtiles;
  int bn = wgid / mtiles;
  int m0 = bm << 7, n0 = bn << 7;
  int wr = (w >> 1) * 64, wc = (w & 1) * 64;

  const f32x4 fz = {0.f, 0.f, 0.f, 0.f};
  f32x4 acc[4][4];
#pragma unroll
  for (int i = 0; i < 4; i++)
#pragma unroll
    for (int j = 0; j < 4; j++) acc[i][j] = fz;

  for (int k0 = 0; k0 < K; k0 += 32) {
    __syncthreads();
#pragma unroll
    for (int i = 0; i < 2; i++) {
      int idx = i * 256 + tid;
      int r = idx >> 2, c = idx & 3;
      int csrc = c ^ ((r >> 1) & 3);          // 2-way swizzle (bank-free)
      gload_lds16(A + (size_t)(m0 + r) * K + k0 + csrc * 8, As + idx * 16);
      gload_lds16(Bt + (size_t)(n0 + r) * K + k0 + csrc * 8, Bs + idx * 16);
    }
    __syncthreads();
    s16x8 af[4], bf[4];
    int g = lane >> 4;
#pragma unroll
    for (int mi = 0; mi < 4; mi++) {
      int r = wr + mi * 16 + (lane & 15);
      af[mi] = *(const s16x8*)(As + r * 64 + ((g ^ ((r >> 1) & 3)) << 4));
    }
#pragma unroll
    for (int ni = 0; ni < 4; ni++) {
      int r = wc + ni * 16 + (lane & 15);
      bf[ni] = *(const s16x8*)(Bs + r * 64 + ((g ^ ((r >> 1) & 3)) << 4));
    }
#pragma unroll
    for (int mi = 0; mi < 4; mi++)
#pragma unroll
      for (int ni = 0; ni < 4; ni++)
        acc[mi][ni] = __builtin_amdgcn_mfma_f32_16x16x32_bf16(af[mi], bf[ni], acc[mi][ni], 0, 0, 0);
  }
#pragma unroll
  for (int mi = 0; mi < 4; mi++)
#pragma unroll
    for (int ni = 0; ni < 4; ni++) {
      int row0 = m0 + wr + mi * 16 + ((lane >> 4) << 2);
      int col = n0 + wc + ni * 16 + (lane & 15);
#pragma unroll
      for (int j = 0; j < 4; j++) {
        if constexpr (sizeof(CT) == 2)
          C[(size_t)(row0 + j) * N + col] = f2bf(acc[mi][ni][j]);
        else
          C[(size_t)(row0 + j) * N + col] = acc[mi][ni][j];
      }
    }
}

// ------------------------------------------------- fused RMSNorm + RoPE for Q and K
// wave-per-row over bf16 Cqkv. Q rows: B*S*H (65536), then K rows: B*S*KV (16384)
__global__ __launch_bounds__(256) void qk_norm_rope(const u16t* __restrict__ Cqkv,
                                                    const float* __restrict__ rope,
                                                    const float* __restrict__ qw,
                                                    const float* __restrict__ kw,
                                                    u16t* __restrict__ Qb,   // (B,H,S,D)
                                                    u16t* __restrict__ Kb,   // (B,KV,S,D)
                                                    u16t* __restrict__ Gs,   // (B,S,H*D)
                                                    float* __restrict__ present) {
  int wid = blockIdx.x * 4 + (threadIdx.x >> 6);
  int lane = threadIdx.x & 63;
  const int NQ = BB * SS * HH; // 65536
  if (wid < NQ) {
    int b = wid >> 15;          // S*H = 32768
    int rem = wid & 32767;
    int s = rem >> 4, h = rem & 15;
    const u16t* base = Cqkv + (size_t)(b * SS + s) * NQKV + h * 256;
    float xlo = bf2f(base[lane]), xhi = bf2f(base[64 + lane]);
    float ss = xlo * xlo + xhi * xhi;
    ss += __shfl_xor(ss, 1);  ss += __shfl_xor(ss, 2);  ss += __shfl_xor(ss, 4);
    ss += __shfl_xor(ss, 8);  ss += __shfl_xor(ss, 16); ss += __shfl_xor(ss, 32);
    float r = rsqrtf(ss * (1.f / 128.f) + 1e-6f);
    float qlo = xlo * r * (1.f + qw[lane]);
    float qhi = xhi * r * (1.f + qw[64 + lane]);
    const float* cs = rope + (size_t)s * 256;
    float clo = cs[lane], chi = cs[64 + lane];
    float slo = cs[128 + lane], shi = cs[192 + lane];
    const float SC = 0.08838834764831845f; // 1/sqrt(128), folded into Q
    float olo = (qlo * clo - qhi * slo) * SC;
    float ohi = (qhi * chi + qlo * shi) * SC;
    size_t qoff = (((size_t)b * HH + h) * SS + s) * DD;
    Qb[qoff + lane] = f2bf(olo);
    Qb[qoff + 64 + lane] = f2bf(ohi);
    float glo = bf2f(base[128 + lane]), ghi = bf2f(base[192 + lane]);
    size_t goff = ((size_t)(b * SS + s)) * (HH * DD) + h * DD;
    Gs[goff + lane] = f2bf(1.f / (1.f + __expf(-glo)));
    Gs[goff + 64 + lane] = f2bf(1.f / (1.f + __expf(-ghi)));
  } else {
    int wid2 = wid - NQ;        // (b, s, kv): per b = S*KV = 8192
    int b = wid2 >> 13;
    int rem = wid2 & 8191;
    int s = rem >> 2, kv = rem & 3;
    const u16t* base = Cqkv + (size_t)(b * SS + s) * NQKV + 4096 + kv * 128;
    float xlo = bf2f(base[lane]), xhi = bf2f(base[64 + lane]);
    float ss = xlo * xlo + xhi * xhi;
    ss += __shfl_xor(ss, 1);  ss += __shfl_xor(ss, 2);  ss += __shfl_xor(ss, 4);
    ss += __shfl_xor(ss, 8);  ss += __shfl_xor(ss, 16); ss += __shfl_xor(ss, 32);
    float r = rsqrtf(ss * (1.f / 128.f) + 1e-6f);
    float klo = xlo * r * (1.f + kw[lane]);
    float khi = xhi * r * (1.f + kw[64 + lane]);
    const float* cs = rope + (size_t)s * 256;
    float clo = cs[lane], chi = cs[64 + lane];
    float slo = cs[128 + lane], shi = cs[192 + lane];
    float olo = klo * clo - khi * slo;
    float ohi = khi * chi + klo * shi;
    size_t koff = (((size_t)b * KVH + kv) * SS + s) * DD;
    Kb[koff + lane] = f2bf(olo);
    Kb[koff + 64 + lane] = f2bf(ohi);
    // present[b][0][kv][s][d]
    size_t poff = (((size_t)(b * 2 * KVH + kv)) * SS + s) * DD;
    present[poff + lane] = olo;
    present[poff + 64 + lane] = ohi;
  }
}

// ------------------------------------------------- V: present write + V^T bf16 (B,KV,D,S)
__global__ __launch_bounds__(256) void v_write(const u16t* __restrict__ Cqkv,
                                               float* __restrict__ present,
                                               u16t* __restrict__ Vtb) {
  __shared__ float lds[128 * 65];
  int t = threadIdx.x;
  int b = blockIdx.x >> 7;
  int kv = (blockIdx.x >> 5) & 3;
  int s0 = (blockIdx.x & 31) << 6;
#pragma unroll
  for (int i = 0; i < 32; i++) {
    int idx = i * 256 + t;
    int sp = idx >> 7, d = idx & 127;
    float v = bf2f(Cqkv[(size_t)(b * SS + s0 + sp) * NQKV + 4608 + kv * 128 + d]);
    // present[b][1][kv][s][d]
    present[(((size_t)(b * 2 * KVH + KVH + kv)) * SS + s0 + sp) * DD + d] = v;
    lds[d * 65 + sp] = v;
  }
  __syncthreads();
#pragma unroll
  for (int i = 0; i < 8; i++) {
    int d = i * 16 + (t >> 4);
    int sp = (t & 15) * 4;
    s16x4 pk;
    pk[0] = (short)f2bf(lds[d * 65 + sp + 0]);
    pk[1] = (short)f2bf(lds[d * 65 + sp + 1]);
    pk[2] = (short)f2bf(lds[d * 65 + sp + 2]);
    pk[3] = (short)f2bf(lds[d * 65 + sp + 3]);
    *(s16x4*)(Vtb + ((size_t)(b * KVH + kv) * DD + d) * SS + s0 + sp) = pk;
  }
}

// ---------------------------------------------------------------- flash attention
// block = 4 waves; KVBLK=64; causal. PAIRED q-tiles: block handles qt = 31-p then
// qt = p sequentially -> exactly 33 KV-tile-units per block, every block equal.
// Grid = B*KV*4h*16p = 512 = 2 blocks/CU; uniform duration, occupancy constant.
// K/V double-buffered (LDS 72KB -> 2 blocks/CU): next tile's stage issued at top
// of iteration, single vmcnt(0)+barrier at bottom -> stage hidden under compute.
__global__ __launch_bounds__(256) void attn_kernel(const u16t* __restrict__ Qb,   // (B,H,S,D) pre-scaled
                                                   const u16t* __restrict__ Kb,   // (B,KV,S,D)
                                                   const u16t* __restrict__ Vtb,  // (B,KV,D,S)
                                                   const u16t* __restrict__ Gs,   // (B,S,H*D)
                                                   u16t* __restrict__ AttG) {     // (B,S,H*D)
  __shared__ __align__(16) char Ks[2][16384];   // 64 rows x 256B, chunk xor (r&7)
  __shared__ __align__(16) char Vs[2][16384];   // V^T: 128 rows x 128B, chunk xor (d&7)
  __shared__ __align__(16) char Ps[4 * 2048];   // per-wave P: 16 rows x 128B, chunk xor

  int tid = threadIdx.x, lane = tid & 63, w = tid >> 6;
  int x = blockIdx.x & 7;          // XCD grouping: each XCD owns one (b,kv)
  int b = x >> 2, kv = x & 3;
  int rr = blockIdx.x >> 3;        // 0..63
  int h = kv * 4 + (rr & 3);
  int p = rr >> 2;                 // 0..15: pair {31-p, p}

  const u16t* Kbase = Kb + (((size_t)(b * KVH + kv)) * SS) * DD;
  const u16t* Vbase = Vtb + (((size_t)(b * KVH + kv)) * DD) * SS;

  auto stageK = [&](int kt, int buf) {
#pragma unroll
    for (int i = 0; i < 4; i++) {
      int idx = i * 256 + tid;
      int r_ = idx >> 4, c_ = idx & 15;
      gload_lds16(Kbase + (size_t)(kt * 64 + r_) * DD + (c_ ^ (r_ & 7)) * 8, Ks[buf] + idx * 16);
    }
  };
  auto stageV = [&](int kt, int buf) {
#pragma unroll
    for (int i = 0; i < 4; i++) {
      int idx = i * 256 + tid;
      int r_ = idx >> 3, c_ = idx & 7;
      gload_lds16(Vbase + (size_t)r_ * SS + kt * 64 + (c_ ^ (r_ & 7)) * 8, Vs[buf] + idx * 16);
    }
  };

  const f32x4 fz = {0.f, 0.f, 0.f, 0.f};
  char* pbase = Ps + w * 2048;
  int cur = 0;

  // prologue: stage tile 0 of segment 0 into buffer 0
  stageK(0, 0);
  stageV(0, 0);

  for (int seg = 0; seg < 2; seg++) {
    int qt = (seg == 0) ? (31 - p) : p;
    const u16t* Qbase = Qb + (((size_t)(b * HH + h)) * SS + qt * 64) * DD;
    s16x8 qf[4];
    {
      const u16t* qrow = Qbase + (size_t)(w * 16 + (lane & 15)) * DD + (lane >> 4) * 8;
#pragma unroll
      for (int ks = 0; ks < 4; ks++) qf[ks] = *(const s16x8*)(qrow + ks * 32);
    }
    f32x4 acco[8];
#pragma unroll
    for (int f = 0; f < 8; f++) acco[f] = fz;
    float mrun[4], lrun[4];
#pragma unroll
    for (int j = 0; j < 4; j++) { mrun[j] = -INFINITY; lrun[j] = 0.f; }

    if (seg == 0) {
      asm volatile("s_waitcnt vmcnt(0)" ::: "memory");
      __builtin_amdgcn_s_barrier();
    }

    for (int kt = 0; kt <= qt; kt++) {
      bool havenext = (kt < qt) || (seg == 0);
      if (havenext) {
        int nk = (kt < qt) ? (kt + 1) : 0;   // next tile, or seg1's tile 0
        stageK(nk, cur ^ 1);
        stageV(nk, cur ^ 1);
      }
      // ---- QK^T from Ks[cur]
      f32x4 accs[4];
#pragma unroll
      for (int ni = 0; ni < 4; ni++) accs[ni] = fz;
#pragma unroll
      for (int ni = 0; ni < 4; ni++) {
        int r = ni * 16 + (lane & 15);
#pragma unroll
        for (int ks = 0; ks < 4; ks++) {
          int g = ks * 4 + (lane >> 4);
          s16x8 bfk = *(const s16x8*)(Ks[cur] + r * 256 + ((g ^ (r & 7)) << 4));
          accs[ni] = __builtin_amdgcn_mfma_f32_16x16x32_bf16(qf[ks], bfk, accs[ni], 0, 0, 0);
        }
      }
      if (kt == qt) {
#pragma unroll
        for (int ni = 0; ni < 4; ni++) {
          int col = ni * 16 + (lane & 15);
#pragma unroll
          for (int j = 0; j < 4; j++) {
            int row = w * 16 + ((lane >> 4) << 2) + j;
            if (col > row) accs[ni][j] = -1e30f;
          }
        }
      }
      // ---- online softmax
      float mt[4];
#pragma unroll
      for (int j = 0; j < 4; j++) {
        float v = fmaxf(fmaxf(accs[0][j], accs[1][j]), fmaxf(accs[2][j], accs[3][j]));
        v = fmaxf(v, __shfl_xor(v, 1));
        v = fmaxf(v, __shfl_xor(v, 2));
        v = fmaxf(v, __shfl_xor(v, 4));
        v = fmaxf(v, __shfl_xor(v, 8));
        mt[j] = v;
      }
      float alpha[4];
#pragma unroll
      for (int j = 0; j < 4; j++) {
        float mnew = fmaxf(mrun[j], mt[j]);
        alpha[j] = __expf(mrun[j] - mnew);
        mrun[j] = mnew;
      }
      float rs[4] = {0.f, 0.f, 0.f, 0.f};
#pragma unroll
      for (int ni = 0; ni < 4; ni++)
#pragma unroll
        for (int j = 0; j < 4; j++) {
          float pv = __expf(accs[ni][j] - mrun[j]);
          accs[ni][j] = pv;
          rs[j] += pv;
        }
#pragma unroll
      for (int j = 0; j < 4; j++) {
        float v = rs[j];
        v += __shfl_xor(v, 1); v += __shfl_xor(v, 2);
        v += __shfl_xor(v, 4); v += __shfl_xor(v, 8);
        lrun[j] = lrun[j] * alpha[j] + v;
      }
#pragma unroll
      for (int f = 0; f < 8; f++)
#pragma unroll
        for (int j = 0; j < 4; j++) acco[f][j] *= alpha[j];

      // ---- P -> LDS (per-wave region)
#pragma unroll
      for (int ni = 0; ni < 4; ni++)
#pragma unroll
        for (int j = 0; j < 4; j++) {
          int row = ((lane >> 4) << 2) + j, col = ni * 16 + (lane & 15);
          int ch = (col >> 3) ^ (row & 7);
          *(u16t*)(pbase + row * 128 + ch * 16 + (col & 7) * 2) = f2bf(accs[ni][j]);
        }
      // ---- PV from Vs[cur]
#pragma unroll
      for (int ks = 0; ks < 2; ks++) {
        int pr = lane & 15;
        int pch = (ks * 4 + (lane >> 4)) ^ (pr & 7);
        s16x8 pa = *(const s16x8*)(pbase + pr * 128 + (pch << 4));
#pragma unroll
        for (int f = 0; f < 8; f++) {
          int d = f * 16 + (lane & 15);
          int g = ks * 4 + (lane >> 4);
          s16x8 vf = *(const s16x8*)(Vs[cur] + d * 128 + ((g ^ (d & 7)) << 4));
          acco[f] = __builtin_amdgcn_mfma_f32_16x16x32_bf16(pa, vf, acco[f], 0, 0, 0);
        }
      }
      // ---- tile boundary: next tile staged, current reads done
      if (havenext) {
        asm volatile("s_waitcnt vmcnt(0)" ::: "memory");
        __builtin_amdgcn_s_barrier();
        cur ^= 1;
      }
    }
    // ---- segment epilogue
#pragma unroll
    for (int f = 0; f < 8; f++) {
      int d = f * 16 + (lane & 15);
#pragma unroll
      for (int j = 0; j < 4; j++) {
        int srow = qt * 64 + w * 16 + ((lane >> 4) << 2) + j;
        float o = acco[f][j] / lrun[j];
        size_t off = ((size_t)b * SS + srow) * (HH * DD) + h * DD + d;
        float g = bf2f(Gs[off]);
        AttG[off] = f2bf(o * g);
      }
    }
  }
}

// ---------------------------------------------------------------- launcher
extern "C" void kernel_launch(void* const* d_in, const int* in_sizes, int n_in,
                              void* d_out, int out_size, void* d_ws, size_t ws_size,
                              hipStream_t stream) {
  const float* hidden = (const float*)d_in[0];
  const float* rope   = (const float*)d_in[2];
  const float* Wq     = (const float*)d_in[5];
  const float* Wk     = (const float*)d_in[6];
  const float* Wv     = (const float*)d_in[7];
  const float* Wo     = (const float*)d_in[8];
  const float* qw     = (const float*)d_in[9];
  const float* kw     = (const float*)d_in[10];
  float* out = (float*)d_out;
  float* present = out + (size_t)BB * SS * HIDD; // 8,388,608

  char* ws = (char*)d_ws;
  u16t* Xb    = (u16t*)(ws);                              // 4096x2048 bf16   16.78MB
  u16t* Wt    = (u16t*)(ws + 16777216);                   // 5120x2048 bf16   20.97MB
  u16t* Wot   = (u16t*)(ws + 37748736);                   // 2048x2048 bf16    8.39MB
  u16t* Cqkv  = (u16t*)(ws + 46137344);                   // 4096x5120 bf16   41.94MB
  u16t* Qb    = (u16t*)(ws + 88080384);                   // (B,H,S,D) bf16   16.78MB
  u16t* Kb    = (u16t*)(ws + 104857600);                  // (B,KV,S,D) bf16   4.19MB
  u16t* Vtb   = (u16t*)(ws + 109051904);                  // (B,KV,D,S) bf16   4.19MB
  u16t* Gs    = (u16t*)(ws + 113246208);                  // (B,S,H*D) bf16   16.78MB
  u16t* AttG  = Xb;  // alias: Xb dead after QKV GEMM; AttG written by attention

  // 1. cast hidden -> bf16
  cast_x<<<8192, 256, 0, stream>>>(hidden, Xb);
  // 2. transpose-cast weights into B^T layout
  transpose_cast<<<(4096 / 64) * 32, 256, 0, stream>>>(Wq, Wt, 4096);
  transpose_cast<<<(512 / 64) * 32, 256, 0, stream>>>(Wk, Wt + (size_t)4096 * HIDD, 512);
  transpose_cast<<<(512 / 64) * 32, 256, 0, stream>>>(Wv, Wt + (size_t)4608 * HIDD, 512);
  transpose_cast<<<(2048 / 64) * 32, 256, 0, stream>>>(Wo, Wot, 2048);
  // 3. QKV projection: 128^2 m97-structure GEMM, grid 32x40 = 1280 = 5 blocks/CU exact
  gemm_bt<u16t><<<(MM / 128) * (NQKV / 128), 256, 0, stream>>>(Xb, Wt, Cqkv, MM, NQKV, HIDD);
  // 4. Q/K norm+rope (+present K, +sigmoid gate); V writer (+present V, +V^T)
  qk_norm_rope<<<(BB * SS * (HH + KVH)) / 4, 256, 0, stream>>>(Cqkv, rope, qw, kw, Qb, Kb, Gs, present);
  v_write<<<BB * KVH * (SS / 64), 256, 0, stream>>>(Cqkv, present, Vtb);
  // 5. flash attention: paired q-tiles, 512 uniform blocks
  attn_kernel<<<BB * HH * (SS / 128), 256, 0, stream>>>(Qb, Kb, Vtb, Gs, AttG);
  // 6. output projection -> d_out: grid 32x16 = 512 = 2 blocks/CU all-resident
  gemm_bt<float><<<(MM / 128) * (HIDD / 128), 256, 0, stream>>>(AttG, Wot, out, MM, HIDD, HIDD);
}